// Round 2
// 212.988 us; speedup vs baseline: 1.1951x; 1.1951x over previous
//
#include <hip/hip_runtime.h>

// n=2048 rows, f=32 features. Output row r = [emb[i] (32) | emb[j] (32) | sw[j]],
// i = r>>11, j = r&2047. Output = 2048*2048*65 floats = 1.09 GB, write-BW bound.
//
// v2b: wave-autonomous subtiles, NO __syncthreads. (v2 + native-vector fix for
// __builtin_nontemporal_store, which rejects HIP_vector_type float4.)
//
// Block = 256 threads = 4 waves; block tile = 64 rows; each wave owns 16 rows
// (1040 floats = 4160 B of LDS) and fills + drains ONLY its own slice, with a
// wave-local s_waitcnt lgkmcnt(0) between the phases. This removes the
// fill/drain phase convoy that left HBM idle during every block's fill phase.
//
// Fill is vectorized: the wave's emb[j0..j0+15] slab (2048 B) is read as two
// coalesced float4 wave-loads and scattered into the 65-stride LDS image with
// ds_write_b32 (worst 2-way bank aliasing = free). emb[i] is one register,
// replicated by all 64 lanes. sw written by 16 lanes in parallel.
//
// Drain: 260 float4/wave, unit-stride ds_read_b128 + nontemporal
// global_store_dwordx4 (output is write-once, never re-read -> keep L2 clean).

#define NROWS 2048u
#define WAVE_ROWS 16u
#define WAVE_FLOATS (WAVE_ROWS * 65u)    // 1040 floats = 4160 B per wave
#define WAVE_F4 (WAVE_FLOATS / 4u)       // 260 float4, exact
#define TILE_ROWS 64u                    // per block (4 waves)
#define TILE_F4 (TILE_ROWS * 65u / 4u)   // 1040 float4 per block

typedef float f32x4 __attribute__((ext_vector_type(4)));

__global__ __launch_bounds__(256) void expand_wave(
    const float* __restrict__ emb,   // [2048*32]
    const float* __restrict__ sw,    // [2048]
    f32x4* __restrict__ out)         // flat output as float4
{
    __shared__ __align__(16) float lds[4 * WAVE_FLOATS];   // 16,640 B

    const unsigned tid  = threadIdx.x;
    const unsigned wave = tid >> 6;
    const unsigned lane = tid & 63u;

    // Wave's first output row. Block spans 64 aligned rows -> i constant,
    // j-range j0..j0+15 never wraps (16 | 2048).
    const unsigned r0 = blockIdx.x * TILE_ROWS + wave * WAVE_ROWS;
    const unsigned i  = r0 >> 11;
    const unsigned j0 = r0 & (NROWS - 1u);

    float* wlds = lds + wave * WAVE_FLOATS;

    // ---- fill: b-part. emb rows j0..j0+15 = 512 floats = 128 float4,
    //      contiguous in global memory -> 2 coalesced wave-loads.
    const f32x4* embj = (const f32x4*)(emb + (size_t)j0 * 32u);
    const f32x4 b0 = embj[lane];
    const f32x4 b1 = embj[lane + 64u];

    {
        // global f4 index g within the slab: row = g>>3, col = (g&7)*4.
        // LDS float addr = row*65 + 32 + col  (4 consecutive floats).
        unsigned g = lane;
        unsigned d = (g >> 3) * 65u + 32u + (g & 7u) * 4u;
        wlds[d + 0u] = b0.x; wlds[d + 1u] = b0.y;
        wlds[d + 2u] = b0.z; wlds[d + 3u] = b0.w;
        g = lane + 64u;
        d = (g >> 3) * 65u + 32u + (g & 7u) * 4u;
        wlds[d + 0u] = b1.x; wlds[d + 1u] = b1.y;
        wlds[d + 2u] = b1.z; wlds[d + 3u] = b1.w;
    }

    // ---- fill: a-part. All 64 lanes useful: lanes 0-31 rows 0-7,
    //      lanes 32-63 rows 8-15, col = lane&31. 8 ds_write_b32 per lane.
    const float vi = emb[i * 32u + (lane & 31u)];
    const unsigned rbase = (lane >> 5) * 8u;
#pragma unroll
    for (unsigned rp = 0; rp < 8u; ++rp)
        wlds[(rbase + rp) * 65u + (lane & 31u)] = vi;

    // ---- fill: sw column, 16 lanes in parallel.
    if (lane < WAVE_ROWS)
        wlds[lane * 65u + 64u] = sw[j0 + lane];

    // Wave-local fill->drain ordering; no inter-wave sync needed since each
    // wave touches only its own LDS slice. "memory" clobber pins the
    // ds_writes above / ds_reads below this point.
    asm volatile("s_waitcnt lgkmcnt(0)" ::: "memory");

    // ---- drain: 260 float4, unit-stride, nontemporal stores.
    const f32x4* wlds4 = (const f32x4*)wlds;
    const unsigned obase = blockIdx.x * TILE_F4 + wave * WAVE_F4;
#pragma unroll
    for (unsigned p = 0; p < 4u; ++p) {
        const unsigned idx = p * 64u + lane;
        __builtin_nontemporal_store(wlds4[idx], &out[obase + idx]);
    }
    if (lane < 4u) {
        const unsigned idx = 256u + lane;
        __builtin_nontemporal_store(wlds4[idx], &out[obase + idx]);
    }
}

extern "C" void kernel_launch(void* const* d_in, const int* in_sizes, int n_in,
                              void* d_out, int out_size, void* d_ws, size_t ws_size,
                              hipStream_t stream) {
    const float* emb = (const float*)d_in[0];   // [2048, 32] f32
    const float* sw  = (const float*)d_in[1];   // [2048] f32
    f32x4* out       = (f32x4*)d_out;

    const unsigned tiles = (NROWS * NROWS) / TILE_ROWS;   // 65,536 blocks
    expand_wave<<<dim3(tiles), dim3(256), 0, stream>>>(emb, sw, out);
}

// Round 3
// 207.097 us; speedup vs baseline: 1.2291x; 1.0284x over previous
//
#include <hip/hip_runtime.h>

// n=2048 rows, f=32 features. Output row r = [emb[i] (32) | emb[j] (32) | sw[j]],
// i = r>>11, j = r&2047. Output = 2048*2048*65 floats = 1.09 GB, write-BW bound.
//
// v3: intra-wave software pipeline, double-buffered LDS, no syncs at all.
// v2 removed the intra-block fill/drain barrier, but blocks on a CU launch as
// a cohort with identical durations -> fill phases stay phase-correlated and
// HBM idles ~20% of the time (measured 5.1 of 6.5 TB/s memset ceiling).
// Here each wave owns 128 consecutive output rows = 8 slabs of 16 rows and
// pipelines them through 2 private LDS buffers:
//    prefetch slab s+1 (global->regs)  ||  drain slab s (LDS->HBM, nt)
//    ||  scatter slab s+1 regs -> other buffer
// The store stream per wave has no structural gaps -> duty cycle ~95%.
//
// The a-part (emb[i], 32 floats) is wave-uniform and written into both
// buffers ONCE in the prologue; steady-state fill is only the b-part scatter
// (8 ds_write_b32) + sw. All LDS traffic is wave-private (no __syncthreads).
//
// LDS: 4 waves x 2 bufs x 4160 B = 33,280 B -> 4 blocks/CU (16 waves), with
// latency hiding now coming from the intra-wave pipeline rather than TLP.

#define NROWS 2048u
#define BLOCK_ROWS 512u                 // per block (4 waves x 128 rows)
#define WAVE_ROWS 128u                  // per wave
#define SLAB_ROWS 16u
#define NSLABS 8u                       // 128/16
#define SLAB_FLOATS (SLAB_ROWS * 65u)   // 1040 floats = 4160 B
#define SLAB_F4 (SLAB_FLOATS / 4u)      // 260 float4, exact

typedef float f32x4 __attribute__((ext_vector_type(4)));

__global__ __launch_bounds__(256) void expand_pipe(
    const float* __restrict__ emb,   // [2048*32]
    const float* __restrict__ sw,    // [2048]
    f32x4* __restrict__ out)         // flat output as float4
{
    __shared__ __align__(16) float lds[4][2][SLAB_FLOATS];   // 33,280 B

    const unsigned tid  = threadIdx.x;
    const unsigned wave = tid >> 6;
    const unsigned lane = tid & 63u;

    // Wave's first output row. 128-aligned, 128 | 2048 -> i constant for the
    // whole wave, j-range j0..j0+127 contiguous (never wraps).
    const unsigned r0 = blockIdx.x * BLOCK_ROWS + wave * WAVE_ROWS;
    const unsigned i  = r0 >> 11;
    const unsigned j0 = r0 & (NROWS - 1u);

    // ---- prologue: a-part. emb[i] is constant for all 128 rows: write cols
    // 0..31 of all 16 slab-rows into BOTH buffers once. Lanes 0-31 rows 0-7,
    // lanes 32-63 rows 8-15, col = lane&31.
    const float vi = emb[i * 32u + (lane & 31u)];
    const unsigned rbase = (lane >> 5) * 8u;
#pragma unroll
    for (unsigned b = 0; b < 2u; ++b)
#pragma unroll
        for (unsigned rp = 0; rp < 8u; ++rp)
            lds[wave][b][(rbase + rp) * 65u + (lane & 31u)] = vi;

    // Static scatter destination for the b-part: global f4 index g in the
    // 128-f4 slab maps to LDS float addr (g>>3)*65 + 32 + (g&7)*4.
    // For g = lane+64 the addr is just d0 + 8*65.
    const unsigned d0 = (lane >> 3) * 65u + 32u + (lane & 7u) * 4u;

    // ---- prologue: prefetch + scatter slab 0 into buffer 0.
    {
        const f32x4* ej = (const f32x4*)(emb + (size_t)j0 * 32u);
        const f32x4 pa = ej[lane];
        const f32x4 pb = ej[lane + 64u];
        const float ps = sw[j0 + (lane & 15u)];
        float* B = &lds[wave][0][0];
        B[d0 + 0u] = pa.x; B[d0 + 1u] = pa.y;
        B[d0 + 2u] = pa.z; B[d0 + 3u] = pa.w;
        B[d0 + 520u + 0u] = pb.x; B[d0 + 520u + 1u] = pb.y;
        B[d0 + 520u + 2u] = pb.z; B[d0 + 520u + 3u] = pb.w;
        if (lane < 16u) B[lane * 65u + 64u] = ps;
    }

    // ---- pipelined main loop over 8 slabs (fully unrolled, static buffers).
#pragma unroll
    for (unsigned s = 0; s < NSLABS; ++s) {
        const unsigned cur = s & 1u;

        // prefetch slab s+1 -> registers (independent of the drain below;
        // scheduler hoists the loads so latency hides under the stores)
        f32x4 pa, pb;
        float ps = 0.0f;
        if (s + 1u < NSLABS) {
            const f32x4* ej =
                (const f32x4*)(emb + (size_t)(j0 + (s + 1u) * SLAB_ROWS) * 32u);
            pa = ej[lane];
            pb = ej[lane + 64u];
            ps = sw[j0 + (s + 1u) * SLAB_ROWS + (lane & 15u)];
        }

        // drain buffer `cur` (slab s): 260 float4, unit stride, nontemporal.
        const f32x4* L4 = (const f32x4*)&lds[wave][cur][0];
        const unsigned obase = ((r0 + s * SLAB_ROWS) >> 4) * SLAB_F4;
#pragma unroll
        for (unsigned p = 0; p < 4u; ++p)
            __builtin_nontemporal_store(L4[p * 64u + lane],
                                        &out[obase + p * 64u + lane]);
        if (lane < 4u)
            __builtin_nontemporal_store(L4[256u + lane],
                                        &out[obase + 256u + lane]);

        // scatter prefetched slab s+1 into the other buffer.
        if (s + 1u < NSLABS) {
            float* B = &lds[wave][cur ^ 1u][0];
            B[d0 + 0u] = pa.x; B[d0 + 1u] = pa.y;
            B[d0 + 2u] = pa.z; B[d0 + 3u] = pa.w;
            B[d0 + 520u + 0u] = pb.x; B[d0 + 520u + 1u] = pb.y;
            B[d0 + 520u + 2u] = pb.z; B[d0 + 520u + 3u] = pb.w;
            if (lane < 16u) B[lane * 65u + 64u] = ps;
        }
    }
}

extern "C" void kernel_launch(void* const* d_in, const int* in_sizes, int n_in,
                              void* d_out, int out_size, void* d_ws, size_t ws_size,
                              hipStream_t stream) {
    const float* emb = (const float*)d_in[0];   // [2048, 32] f32
    const float* sw  = (const float*)d_in[1];   // [2048] f32
    f32x4* out       = (f32x4*)d_out;

    const unsigned blocks = (NROWS * NROWS) / BLOCK_ROWS;   // 8192
    expand_pipe<<<dim3(blocks), dim3(256), 0, stream>>>(emb, sw, out);
}